// Round 5
// baseline (98.012 us; speedup 1.0000x reference)
//
#include <hip/hip_runtime.h>

// Cubic Bezier spline evaluation, round 5.
// t: (N,) SORTED fp32 in [0,1); ctrl: (S*2, 2) fp32; joint: (S+1, 2) fp32.
// out: (N, 2) fp32.
//
// Round-4 wave-uniform scalar path kept (t sorted => most waves sit in one
// segment; gather + coefficient assembly done once per wave in SGPRs).
// New in round 5: 4 samples/thread — one b128 t-load + two b128 stores,
// halving per-sample instruction issue vs round 4 (2 samples/thread).
// A wave now covers 256 consecutive samples; avg segment = 2048 samples,
// so ~87% of waves still take the uniform path.

typedef float v4f __attribute__((ext_vector_type(4)));

__global__ __launch_bounds__(256) void spline_eval(
    const v4f* __restrict__ t4,         // t viewed as float-vec4
    const float4* __restrict__ ctrl4,   // (S,): p1x,p1y,p2x,p2y per segment
    const float2* __restrict__ joint2,  // (S+1,)
    v4f* __restrict__ out4,             // out viewed as float-vec4, 2/thread
    int n4, int n, float Sf, int Smax)  // n4 = ceil(n/4), Smax = S-1
{
    int i = blockIdx.x * blockDim.x + threadIdx.x;
    if (i >= n4) return;

    v4f tv = t4[i];
    float lt[4];
    int   seg[4];

#pragma unroll
    for (int j = 0; j < 4; ++j) {
        // parity: jnp.minimum(t, 1.0-1e-10) -> fp32 min(t, 1.0f)
        float tt = fminf(tv[j], 1.0f);
        float u = Sf * tt;
        float sf = floorf(u);
        float l = u - sf;
        int s = (int)sf;
        if (s > Smax) {            // reference's over-clamp (seg == S)
            s = Smax;
            l = 1.0f;
        }
        seg[j] = s;
        lt[j] = l;
    }

    float rx[4], ry[4];

    int s0 = __builtin_amdgcn_readfirstlane(seg[0]);
    bool mine_uniform = (seg[0] == s0) & (seg[1] == s0) &
                        (seg[2] == s0) & (seg[3] == s0);
    // Full wave in one segment? (partial tail wave fails the ==~0 check
    // since inactive lanes contribute 0 bits -> takes the gather path)
    if (__ballot(mine_uniform) == ~0ull) {
        // --- wave-uniform fast path: scalar gather + scalar coeffs ---
        float2 p0 = joint2[s0];
        float2 p3 = joint2[s0 + 1];
        float4 c  = ctrl4[s0];     // p1 = (c.x,c.y), p2 = (c.z,c.w)

        float c1x = 3.0f * (c.x - p0.x);
        float c2x = 3.0f * (p0.x - 2.0f * c.x + c.z);
        float c3x = (p3.x - p0.x) + 3.0f * (c.x - c.z);
        float c1y = 3.0f * (c.y - p0.y);
        float c2y = 3.0f * (p0.y - 2.0f * c.y + c.w);
        float c3y = (p3.y - p0.y) + 3.0f * (c.y - c.w);

#pragma unroll
        for (int j = 0; j < 4; ++j) {
            float l = lt[j];
            rx[j] = fmaf(l, fmaf(l, fmaf(l, c3x, c2x), c1x), p0.x);
            ry[j] = fmaf(l, fmaf(l, fmaf(l, c3y, c2y), c1y), p0.y);
        }
    } else {
        // --- boundary / tail path: per-lane gathers ---
#pragma unroll
        for (int j = 0; j < 4; ++j) {
            int s = seg[j];
            float l = lt[j];
            float2 p0 = joint2[s];
            float2 p3 = joint2[s + 1];
            float4 c  = ctrl4[s];

            float c1x = 3.0f * (c.x - p0.x);
            float c2x = 3.0f * (p0.x - 2.0f * c.x + c.z);
            float c3x = (p3.x - p0.x) + 3.0f * (c.x - c.z);
            float c1y = 3.0f * (c.y - p0.y);
            float c2y = 3.0f * (p0.y - 2.0f * c.y + c.w);
            float c3y = (p3.y - p0.y) + 3.0f * (c.y - c.w);

            rx[j] = fmaf(l, fmaf(l, fmaf(l, c3x, c2x), c1x), p0.x);
            ry[j] = fmaf(l, fmaf(l, fmaf(l, c3y, c2y), c1y), p0.y);
        }
    }

    int base = 4 * i;
    if (base + 4 <= n) {
        v4f r0 = {rx[0], ry[0], rx[1], ry[1]};
        v4f r1 = {rx[2], ry[2], rx[3], ry[3]};
        out4[2 * i]     = r0;
        out4[2 * i + 1] = r1;
    } else {
        // tail (not hit for N = 8388608)
        float* out = reinterpret_cast<float*>(out4);
        for (int j = 0; j < 4 && base + j < n; ++j) {
            out[2 * (base + j)]     = rx[j];
            out[2 * (base + j) + 1] = ry[j];
        }
    }
}

extern "C" void kernel_launch(void* const* d_in, const int* in_sizes, int n_in,
                              void* d_out, int out_size, void* d_ws, size_t ws_size,
                              hipStream_t stream) {
    const float* t     = (const float*)d_in[0];
    const float* ctrl  = (const float*)d_in[1];  // (S*2, 2)
    const float* joint = (const float*)d_in[2];  // (S+1, 2)
    float* out = (float*)d_out;

    int n = in_sizes[0];
    int S = in_sizes[2] / 2 - 1;

    int n4 = (n + 3) / 4;
    int block = 256;
    int grid = (n4 + block - 1) / block;

    spline_eval<<<grid, block, 0, stream>>>(
        reinterpret_cast<const v4f*>(t),
        reinterpret_cast<const float4*>(ctrl),
        reinterpret_cast<const float2*>(joint),
        reinterpret_cast<v4f*>(out),
        n4, n, (float)S, S - 1);
}